// Round 12
// baseline (37.015 us; speedup 1.0000x reference)
//
#include <hip/hip_runtime.h>

#define Bb 128
#define Ww 128
#define Nn 512
#define ALPHA 0.2f
#define LOG2E 1.44269504088896340736f

typedef __attribute__((ext_vector_type(8))) short short8;
typedef __attribute__((ext_vector_type(4))) float f32x4;

// v_cvt_pk_bf16_f32: packs (lo,hi) -> u32 of 2 bf16 (RNE; matches prior passing rounds)
__device__ __forceinline__ unsigned pk_bf16(float lo, float hi) {
  unsigned r;
  asm("v_cvt_pk_bf16_f32 %0, %1, %2" : "=v"(r) : "v"(lo), "v"(hi));
  return r;
}

// v_exp_f32 computes 2^x on gfx950 (what __expf lowers to, minus the log2e mul)
__device__ __forceinline__ float v_exp2(float x) {
  float r;
  asm("v_exp_f32 %0, %1" : "=v"(r) : "v"(x));
  return r;
}

// ---- dynamic LDS layout (bytes) ----
#define T_OFF   0
#define T_BYTES (64 * 129 * 8 * 2)     // ushort tile[64 jg][129 w][8] = 132096
#define SR_OFF  (T_OFF + T_BYTES)      // float sred[512*8] = 16384
#define S1_OFF  (SR_OFF + 16384)       // float s1s[512]    = 2048
#define S2_OFF  (S1_OFF + 2048)        // float s2s[512]    = 2048
#define CV_OFF  (S2_OFF + 2048)        // float cvs[129]    (pad 528)
#define SMEM5   (CV_OFF + 528)         // 153104 < 160 KiB

// One block = (batch b, i-half). 512 threads = 8 waves, 1 block/CU.
// R10 numerics; x-loads issued BEFORE cvec (latency overlap); exp2-folded softmax.
__launch_bounds__(512, 1)
__global__ void attn_f5(const float* __restrict__ x, const float* __restrict__ Wfc,
                        const float* __restrict__ bfc, const float* __restrict__ attn,
                        float* __restrict__ out) {
  extern __shared__ char smem[];
  ushort* tile = (ushort*)(smem + T_OFF);
  float*  sred = (float*)(smem + SR_OFF);
  float*  s1s  = (float*)(smem + S1_OFF);
  float*  s2s  = (float*)(smem + S2_OFF);
  float*  cvs  = (float*)(smem + CV_OFF);

  const int bid = blockIdx.x;
  const int xcd = bid & 7, idx = bid >> 3;
  const int b  = xcd * 16 + (idx >> 1);      // sibling i-half blocks share an XCD/L2
  const int i0 = (idx & 1) * 256;
  const int t  = threadIdx.x;
  const int wv = t >> 6, lane = t & 63;
  const int wl = lane & 15, lg = lane >> 4;
  const float* xb = x + (size_t)b * (Ww * Nn);
  const int q = t & 63;

  // ---- P-1: issue ALL 32 x float4 loads first (HBM latency overlaps P0 below) ----
  float4 L0[16], L1[16];
#pragma unroll
  for (int k = 0; k < 16; ++k) {
    const float* s = xb + (size_t)(wv + 8 * k) * Nn + 8 * q;
    L0[k] = *reinterpret_cast<const float4*>(s);
    L1[k] = *reinterpret_cast<const float4*>(s + 4);
  }

  // ---- P0: cvec[w] = sum_v a2[v]*Wfc[v][w] (512 threads), c0 = b_fc . a2 ----
  {
    const int wcol = t & 127, vq = t >> 7;
    float p = 0.f;
#pragma unroll 8
    for (int vi = 0; vi < 32; ++vi) {
      const int v = vq * 32 + vi;
      p = fmaf(attn[Ww + v], Wfc[v * Ww + wcol], p);
    }
    sred[t] = p;
    if (t < 64) {
      float c0p = fmaf(bfc[t], attn[Ww + t], bfc[t + 64] * attn[Ww + 64 + t]);
#pragma unroll
      for (int off = 32; off; off >>= 1) c0p += __shfl_xor(c0p, off);
      if (t == 0) cvs[Ww] = c0p;
    }
  }
  __syncthreads();
  if (t < Ww) cvs[t] = sred[t] + sred[t + 128] + sred[t + 256] + sred[t + 384];
  __syncthreads();

  // ---- P1: drain/process the 32 in-flight loads: f32 s1/s2 partials + bf16 tile ----
  float s1p[8] = {0, 0, 0, 0, 0, 0, 0, 0};
  float s2p[8] = {0, 0, 0, 0, 0, 0, 0, 0};
#pragma unroll
  for (int k = 0; k < 16; ++k) {
    const int w = wv + 8 * k;
    const float aw = attn[w];
    const float cw = cvs[w];
    const float4 lo = L0[k], hi = L1[k];
    s1p[0] = fmaf(lo.x, aw, s1p[0]); s1p[1] = fmaf(lo.y, aw, s1p[1]);
    s1p[2] = fmaf(lo.z, aw, s1p[2]); s1p[3] = fmaf(lo.w, aw, s1p[3]);
    s1p[4] = fmaf(hi.x, aw, s1p[4]); s1p[5] = fmaf(hi.y, aw, s1p[5]);
    s1p[6] = fmaf(hi.z, aw, s1p[6]); s1p[7] = fmaf(hi.w, aw, s1p[7]);
    s2p[0] = fmaf(lo.x, cw, s2p[0]); s2p[1] = fmaf(lo.y, cw, s2p[1]);
    s2p[2] = fmaf(lo.z, cw, s2p[2]); s2p[3] = fmaf(lo.w, cw, s2p[3]);
    s2p[4] = fmaf(hi.x, cw, s2p[4]); s2p[5] = fmaf(hi.y, cw, s2p[5]);
    s2p[6] = fmaf(hi.z, cw, s2p[6]); s2p[7] = fmaf(hi.w, cw, s2p[7]);
    uint4 pk;
    pk.x = pk_bf16(lo.x, lo.y); pk.y = pk_bf16(lo.z, lo.w);
    pk.z = pk_bf16(hi.x, hi.y); pk.w = pk_bf16(hi.z, hi.w);
    *reinterpret_cast<uint4*>(tile + ((size_t)q * 129 + w) * 8) = pk;  // conflict-free
  }

  // ---- P2: reduce s1/s2 across the 8 w-groups; scale by log2(e) (exp2 folding) ----
  {
    f32x4* sv = reinterpret_cast<f32x4*>(&sred[t * 8]);
    sv[0] = (f32x4){s1p[0], s1p[1], s1p[2], s1p[3]};
    sv[1] = (f32x4){s1p[4], s1p[5], s1p[6], s1p[7]};
  }
  __syncthreads();
  float red;
  {
    float a = 0.f;
#pragma unroll
    for (int g = 0; g < 8; ++g) a += sred[((g * 64) + (t >> 3)) * 8 + (t & 7)];
    red = a;
  }
  __syncthreads();   // all sred reads done before rewrite
  {
    s1s[t] = red * LOG2E;
    f32x4* sv = reinterpret_cast<f32x4*>(&sred[t * 8]);
    sv[0] = (f32x4){s2p[0], s2p[1], s2p[2], s2p[3]};
    sv[1] = (f32x4){s2p[4], s2p[5], s2p[6], s2p[7]};
  }
  __syncthreads();
  {
    float d = 0.f;
#pragma unroll
    for (int g = 0; g < 8; ++g) d += sred[((g * 64) + (t >> 3)) * 8 + (t & 7)];
    s2s[t] = (d + cvs[Ww]) * LOG2E;
  }
  __syncthreads();

  // ---- P4: MFMA loop; no max subtraction; exp2; denominators via MFMA x ones ----
  // lrelu commutes with the positive log2e scale: exp(lrelu(u)) = exp2(lrelu(u*log2e)).
  float s1i[2];
  s1i[0] = s1s[i0 + wv * 32 + wl];
  s1i[1] = s1s[i0 + wv * 32 + 16 + wl];

  f32x4 acc[2][8];
  f32x4 accl[2];
#pragma unroll
  for (int a = 0; a < 2; ++a) {
    accl[a] = (f32x4){0.f, 0.f, 0.f, 0.f};
#pragma unroll
    for (int f = 0; f < 8; ++f) acc[a][f] = (f32x4){0.f, 0.f, 0.f, 0.f};
  }
  short8 ones;
#pragma unroll
  for (int e = 0; e < 8; ++e) ones[e] = (short)0x3F80;  // bf16 1.0

  for (int jj = 0; jj < 16; ++jj) {
    const int jb = jj * 32 + 8 * lg;  // this lane's 8 consecutive j's
    float sv[8];
    *reinterpret_cast<float4*>(&sv[0]) = *reinterpret_cast<const float4*>(&s2s[jb]);
    *reinterpret_cast<float4*>(&sv[4]) = *reinterpret_cast<const float4*>(&s2s[jb + 4]);
    float p0[8], p1[8];
#pragma unroll
    for (int e = 0; e < 8; ++e) {
      const float u0 = s1i[0] + sv[e];
      p0[e] = v_exp2(fmaxf(u0, ALPHA * u0));   // |u| <~ 16 pre-scaled -> safe
      const float u1 = s1i[1] + sv[e];
      p1[e] = v_exp2(fmaxf(u1, ALPHA * u1));
    }
    short8 af0, af1;
    unsigned* a0u = reinterpret_cast<unsigned*>(&af0);
    unsigned* a1u = reinterpret_cast<unsigned*>(&af1);
    a0u[0] = pk_bf16(p0[0], p0[1]); a0u[1] = pk_bf16(p0[2], p0[3]);
    a0u[2] = pk_bf16(p0[4], p0[5]); a0u[3] = pk_bf16(p0[6], p0[7]);
    a1u[0] = pk_bf16(p1[0], p1[1]); a1u[1] = pk_bf16(p1[2], p1[3]);
    a1u[2] = pk_bf16(p1[4], p1[5]); a1u[3] = pk_bf16(p1[6], p1[7]);

    const ushort* tb = tile + (size_t)(jj * 4 + lg) * 129 * 8;
#pragma unroll
    for (int f = 0; f < 8; ++f) {
      const short8 bfr = *reinterpret_cast<const short8*>(tb + (16 * f + wl) * 8);
      acc[0][f] = __builtin_amdgcn_mfma_f32_16x16x32_bf16(af0, bfr, acc[0][f], 0, 0, 0);
      acc[1][f] = __builtin_amdgcn_mfma_f32_16x16x32_bf16(af1, bfr, acc[1][f], 0, 0, 0);
    }
    accl[0] = __builtin_amdgcn_mfma_f32_16x16x32_bf16(af0, ones, accl[0], 0, 0, 0);
    accl[1] = __builtin_amdgcn_mfma_f32_16x16x32_bf16(af1, ones, accl[1], 0, 0, 0);
  }

  // ---- P6: epilogue — sigmoid via exp2 (log2e folded into invl) ----
  float* outb = out + (size_t)b * (Ww * Nn);
#pragma unroll
  for (int a = 0; a < 2; ++a) {
    float invl[4];
#pragma unroll
    for (int m = 0; m < 4; ++m) invl[m] = LOG2E / accl[a][m];
    const int ibase = i0 + wv * 32 + 16 * a + lg * 4;
#pragma unroll
    for (int f = 0; f < 8; ++f) {
      float4 o;
      o.x = 1.f / (1.f + v_exp2(-(acc[a][f][0] * invl[0])));
      o.y = 1.f / (1.f + v_exp2(-(acc[a][f][1] * invl[1])));
      o.z = 1.f / (1.f + v_exp2(-(acc[a][f][2] * invl[2])));
      o.w = 1.f / (1.f + v_exp2(-(acc[a][f][3] * invl[3])));
      *reinterpret_cast<float4*>(outb + (16 * f + wl) * Nn + ibase) = o;
    }
  }
}

extern "C" void kernel_launch(void* const* d_in, const int* in_sizes, int n_in,
                              void* d_out, int out_size, void* d_ws, size_t ws_size,
                              hipStream_t stream) {
  const float* x    = (const float*)d_in[0];  // (128,128,512)
  const float* Wfc  = (const float*)d_in[1];  // (128,128)
  const float* bfc  = (const float*)d_in[2];  // (128,)
  const float* attn = (const float*)d_in[3];  // (256,1)
  float* out = (float*)d_out;                 // (128,128,512)

  (void)hipFuncSetAttribute(reinterpret_cast<const void*>(&attn_f5),
                            hipFuncAttributeMaxDynamicSharedMemorySize, SMEM5);
  attn_f5<<<256, 512, SMEM5, stream>>>(x, Wfc, bfc, attn, out);
}

// Round 13
// 29.405 us; speedup vs baseline: 1.2588x; 1.2588x over previous
//
#include <hip/hip_runtime.h>

#define Bb 128
#define Ww 128
#define Nn 512
#define ALPHA 0.2f
#define LOG2E 1.44269504088896340736f

typedef __attribute__((ext_vector_type(8))) short short8;
typedef __attribute__((ext_vector_type(4))) float f32x4;

// v_cvt_pk_bf16_f32: packs (lo,hi) -> u32 of 2 bf16 (RNE; matches prior passing rounds)
__device__ __forceinline__ unsigned pk_bf16(float lo, float hi) {
  unsigned r;
  asm("v_cvt_pk_bf16_f32 %0, %1, %2" : "=v"(r) : "v"(lo), "v"(hi));
  return r;
}

// v_exp_f32 computes 2^x on gfx950 (what __expf lowers to, minus the log2e mul)
__device__ __forceinline__ float v_exp2(float x) {
  float r;
  asm("v_exp_f32 %0, %1" : "=v"(r) : "v"(x));
  return r;
}

// ---- dynamic LDS layout (bytes) ----
#define T_OFF   0
#define T_BYTES (64 * 129 * 8 * 2)     // ushort tile[64 jg][129 w][8] = 132096
#define SR_OFF  (T_OFF + T_BYTES)      // float sred[512*8] = 16384
#define S1_OFF  (SR_OFF + 16384)       // float s1s[512]    = 2048
#define S2_OFF  (S1_OFF + 2048)        // float s2s[512]    = 2048
#define CV_OFF  (S2_OFF + 2048)        // float cvs[129]    (pad 528)
#define SMEM6   (CV_OFF + 528)         // 153104 < 160 KiB

// One block = (batch b, i-half). 512 threads = 8 waves, 1 block/CU.
// R10's proven schedule (P0 cvec FIRST — vmcnt is in-order per wave, so x loads
// must NOT be issued before P0's Wfc consumers) + exp2-folded softmax (R12-validated).
__launch_bounds__(512, 1)
__global__ void attn_f6(const float* __restrict__ x, const float* __restrict__ Wfc,
                        const float* __restrict__ bfc, const float* __restrict__ attn,
                        float* __restrict__ out) {
  extern __shared__ char smem[];
  ushort* tile = (ushort*)(smem + T_OFF);
  float*  sred = (float*)(smem + SR_OFF);
  float*  s1s  = (float*)(smem + S1_OFF);
  float*  s2s  = (float*)(smem + S2_OFF);
  float*  cvs  = (float*)(smem + CV_OFF);

  const int bid = blockIdx.x;
  const int xcd = bid & 7, idx = bid >> 3;
  const int b  = xcd * 16 + (idx >> 1);      // sibling i-half blocks share an XCD/L2
  const int i0 = (idx & 1) * 256;
  const int t  = threadIdx.x;
  const int wv = t >> 6, lane = t & 63;
  const int wl = lane & 15, lg = lane >> 4;
  const float* xb = x + (size_t)b * (Ww * Nn);
  const int q = t & 63;

  // ---- P0: cvec[w] = sum_v a2[v]*Wfc[v][w] (512 threads), c0 = b_fc . a2 ----
  {
    const int wcol = t & 127, vq = t >> 7;
    float p = 0.f;
#pragma unroll 8
    for (int vi = 0; vi < 32; ++vi) {
      const int v = vq * 32 + vi;
      p = fmaf(attn[Ww + v], Wfc[v * Ww + wcol], p);
    }
    sred[t] = p;
    if (t < 64) {
      float c0p = fmaf(bfc[t], attn[Ww + t], bfc[t + 64] * attn[Ww + 64 + t]);
#pragma unroll
      for (int off = 32; off; off >>= 1) c0p += __shfl_xor(c0p, off);
      if (t == 0) cvs[Ww] = c0p;
    }
  }
  __syncthreads();
  if (t < Ww) cvs[t] = sred[t] + sred[t + 128] + sred[t + 256] + sred[t + 384];
  __syncthreads();

  // ---- P1: stream x[b]; ALL 32 float4 loads issued upfront (max MLP), then process ----
  // Thread (wv, q): rows w = wv + 8k, n-slice [8q, 8q+8).
  float s1p[8] = {0, 0, 0, 0, 0, 0, 0, 0};
  float s2p[8] = {0, 0, 0, 0, 0, 0, 0, 0};
  {
    float4 L0[16], L1[16];
#pragma unroll
    for (int k = 0; k < 16; ++k) {  // issue phase: 32 loads in flight
      const float* s = xb + (size_t)(wv + 8 * k) * Nn + 8 * q;
      L0[k] = *reinterpret_cast<const float4*>(s);
      L1[k] = *reinterpret_cast<const float4*>(s + 4);
    }
#pragma unroll
    for (int k = 0; k < 16; ++k) {  // drain phase: vmcnt waits overlap younger loads
      const int w = wv + 8 * k;
      const float aw = attn[w];
      const float cw = cvs[w];
      const float4 lo = L0[k], hi = L1[k];
      s1p[0] = fmaf(lo.x, aw, s1p[0]); s1p[1] = fmaf(lo.y, aw, s1p[1]);
      s1p[2] = fmaf(lo.z, aw, s1p[2]); s1p[3] = fmaf(lo.w, aw, s1p[3]);
      s1p[4] = fmaf(hi.x, aw, s1p[4]); s1p[5] = fmaf(hi.y, aw, s1p[5]);
      s1p[6] = fmaf(hi.z, aw, s1p[6]); s1p[7] = fmaf(hi.w, aw, s1p[7]);
      s2p[0] = fmaf(lo.x, cw, s2p[0]); s2p[1] = fmaf(lo.y, cw, s2p[1]);
      s2p[2] = fmaf(lo.z, cw, s2p[2]); s2p[3] = fmaf(lo.w, cw, s2p[3]);
      s2p[4] = fmaf(hi.x, cw, s2p[4]); s2p[5] = fmaf(hi.y, cw, s2p[5]);
      s2p[6] = fmaf(hi.z, cw, s2p[6]); s2p[7] = fmaf(hi.w, cw, s2p[7]);
      uint4 pk;
      pk.x = pk_bf16(lo.x, lo.y); pk.y = pk_bf16(lo.z, lo.w);
      pk.z = pk_bf16(hi.x, hi.y); pk.w = pk_bf16(hi.z, hi.w);
      *reinterpret_cast<uint4*>(tile + ((size_t)q * 129 + w) * 8) = pk;  // conflict-free
    }
  }

  // ---- P2: reduce s1/s2 across the 8 w-groups; scale by log2(e) (exp2 folding) ----
  {
    f32x4* sv = reinterpret_cast<f32x4*>(&sred[t * 8]);
    sv[0] = (f32x4){s1p[0], s1p[1], s1p[2], s1p[3]};
    sv[1] = (f32x4){s1p[4], s1p[5], s1p[6], s1p[7]};
  }
  __syncthreads();
  float red;
  {
    float a = 0.f;
#pragma unroll
    for (int g = 0; g < 8; ++g) a += sred[((g * 64) + (t >> 3)) * 8 + (t & 7)];
    red = a;
  }
  __syncthreads();   // all sred reads done before rewrite
  {
    s1s[t] = red * LOG2E;
    f32x4* sv = reinterpret_cast<f32x4*>(&sred[t * 8]);
    sv[0] = (f32x4){s2p[0], s2p[1], s2p[2], s2p[3]};
    sv[1] = (f32x4){s2p[4], s2p[5], s2p[6], s2p[7]};
  }
  __syncthreads();
  {
    float d = 0.f;
#pragma unroll
    for (int g = 0; g < 8; ++g) d += sred[((g * 64) + (t >> 3)) * 8 + (t & 7)];
    s2s[t] = (d + cvs[Ww]) * LOG2E;
  }
  __syncthreads();

  // ---- P4: MFMA loop; no max subtraction; exp2; denominators via MFMA x ones ----
  // lrelu commutes with the positive log2e scale: exp(lrelu(u)) = exp2(lrelu(u*log2e)).
  float s1i[2];
  s1i[0] = s1s[i0 + wv * 32 + wl];
  s1i[1] = s1s[i0 + wv * 32 + 16 + wl];

  f32x4 acc[2][8];
  f32x4 accl[2];
#pragma unroll
  for (int a = 0; a < 2; ++a) {
    accl[a] = (f32x4){0.f, 0.f, 0.f, 0.f};
#pragma unroll
    for (int f = 0; f < 8; ++f) acc[a][f] = (f32x4){0.f, 0.f, 0.f, 0.f};
  }
  short8 ones;
#pragma unroll
  for (int e = 0; e < 8; ++e) ones[e] = (short)0x3F80;  // bf16 1.0

  for (int jj = 0; jj < 16; ++jj) {
    const int jb = jj * 32 + 8 * lg;  // this lane's 8 consecutive j's
    float sv[8];
    *reinterpret_cast<float4*>(&sv[0]) = *reinterpret_cast<const float4*>(&s2s[jb]);
    *reinterpret_cast<float4*>(&sv[4]) = *reinterpret_cast<const float4*>(&s2s[jb + 4]);
    float p0[8], p1[8];
#pragma unroll
    for (int e = 0; e < 8; ++e) {
      const float u0 = s1i[0] + sv[e];
      p0[e] = v_exp2(fmaxf(u0, ALPHA * u0));   // |u| <~ 16 pre-scaled -> safe
      const float u1 = s1i[1] + sv[e];
      p1[e] = v_exp2(fmaxf(u1, ALPHA * u1));
    }
    short8 af0, af1;
    unsigned* a0u = reinterpret_cast<unsigned*>(&af0);
    unsigned* a1u = reinterpret_cast<unsigned*>(&af1);
    a0u[0] = pk_bf16(p0[0], p0[1]); a0u[1] = pk_bf16(p0[2], p0[3]);
    a0u[2] = pk_bf16(p0[4], p0[5]); a0u[3] = pk_bf16(p0[6], p0[7]);
    a1u[0] = pk_bf16(p1[0], p1[1]); a1u[1] = pk_bf16(p1[2], p1[3]);
    a1u[2] = pk_bf16(p1[4], p1[5]); a1u[3] = pk_bf16(p1[6], p1[7]);

    const ushort* tb = tile + (size_t)(jj * 4 + lg) * 129 * 8;
#pragma unroll
    for (int f = 0; f < 8; ++f) {
      const short8 bfr = *reinterpret_cast<const short8*>(tb + (16 * f + wl) * 8);
      acc[0][f] = __builtin_amdgcn_mfma_f32_16x16x32_bf16(af0, bfr, acc[0][f], 0, 0, 0);
      acc[1][f] = __builtin_amdgcn_mfma_f32_16x16x32_bf16(af1, bfr, acc[1][f], 0, 0, 0);
    }
    accl[0] = __builtin_amdgcn_mfma_f32_16x16x32_bf16(af0, ones, accl[0], 0, 0, 0);
    accl[1] = __builtin_amdgcn_mfma_f32_16x16x32_bf16(af1, ones, accl[1], 0, 0, 0);
  }

  // ---- P6: epilogue — sigmoid via exp2 (log2e folded into invl) ----
  float* outb = out + (size_t)b * (Ww * Nn);
#pragma unroll
  for (int a = 0; a < 2; ++a) {
    float invl[4];
#pragma unroll
    for (int m = 0; m < 4; ++m) invl[m] = LOG2E / accl[a][m];
    const int ibase = i0 + wv * 32 + 16 * a + lg * 4;
#pragma unroll
    for (int f = 0; f < 8; ++f) {
      float4 o;
      o.x = 1.f / (1.f + v_exp2(-(acc[a][f][0] * invl[0])));
      o.y = 1.f / (1.f + v_exp2(-(acc[a][f][1] * invl[1])));
      o.z = 1.f / (1.f + v_exp2(-(acc[a][f][2] * invl[2])));
      o.w = 1.f / (1.f + v_exp2(-(acc[a][f][3] * invl[3])));
      *reinterpret_cast<float4*>(outb + (16 * f + wl) * Nn + ibase) = o;
    }
  }
}

extern "C" void kernel_launch(void* const* d_in, const int* in_sizes, int n_in,
                              void* d_out, int out_size, void* d_ws, size_t ws_size,
                              hipStream_t stream) {
  const float* x    = (const float*)d_in[0];  // (128,128,512)
  const float* Wfc  = (const float*)d_in[1];  // (128,128)
  const float* bfc  = (const float*)d_in[2];  // (128,)
  const float* attn = (const float*)d_in[3];  // (256,1)
  float* out = (float*)d_out;                 // (128,128,512)

  (void)hipFuncSetAttribute(reinterpret_cast<const void*>(&attn_f6),
                            hipFuncAttributeMaxDynamicSharedMemorySize, SMEM6);
  attn_f6<<<256, 512, SMEM6, stream>>>(x, Wfc, bfc, attn, out);
}